// Round 7
// baseline (87.397 us; speedup 1.0000x reference)
//
#include <hip/hip_runtime.h>
#include <hip/hip_bf16.h>

typedef short s16x8 __attribute__((ext_vector_type(8)));
typedef float f32x4 __attribute__((ext_vector_type(4)));
typedef int   i32x4 __attribute__((ext_vector_type(4)));
typedef unsigned short u16;

#define BB 8
#define CC 128
#define HH 48
#define WW 48
#define NN 2304
#define SCALE_L2E 0.12751744f          // log2(e)/sqrt(128)
#define SZ_MAP (BB*CC*NN)              // 2359296 elements
#define NSPLIT 3
#define TILES_PER (18/NSPLIT)

__device__ inline u16 f2bf(float f) {
    unsigned u = __builtin_bit_cast(unsigned, f);
    u = (u + 0x7FFFu + ((u >> 16) & 1u)) >> 16;
    return (u16)u;
}
__device__ inline float bf2f(u16 h) {
    unsigned u = ((unsigned)h) << 16;
    return __builtin_bit_cast(float, u);
}

#define MFMA(a, b, c) __builtin_amdgcn_mfma_f32_16x16x32_bf16(a, b, c, 0, 0, 0)
// DPP rotate-add within each 16-lane row (VALU pipe, no LDS traffic)
#define DPP_ROR_ADD(x, N) { \
    int yi_ = __builtin_amdgcn_update_dpp(0, __builtin_bit_cast(int, x), 0x120 | (N), 0xf, 0xf, true); \
    x += __builtin_bit_cast(float, yi_); }

// ---------------- K1: GroupNorm -> xnT16[b][n][c]  +  weight cast (fused) ----------------
// b = blockIdx.x & 7 so all blocks of batch b land on XCD b (blockid % 8 == b).
__global__ __launch_bounds__(256) void gnprep_kernel(
        const float* __restrict__ x, const float* __restrict__ gw,
        const float* __restrict__ gb, u16* __restrict__ xnT,
        const float* __restrict__ wq, const float* __restrict__ wk,
        const float* __restrict__ wv_, const float* __restrict__ wo,
        u16* __restrict__ w16) {
    int tid = threadIdx.x;
    if (blockIdx.x >= 256) {
        int i = (blockIdx.x - 256) * 256 + tid;   // 0..65535
        int m = i >> 14, r = i & 16383;
        const float* src = (m == 0) ? wq : (m == 1) ? wk : (m == 2) ? wv_ : wo;
        w16[i] = f2bf(src[r]);
        return;
    }
    int b = blockIdx.x & 7, g = blockIdx.x >> 3;
    const float* xb = x + ((size_t)b * CC + g * 4) * NN;
    float v[4][9];
    float s = 0.f, ss = 0.f;
#pragma unroll
    for (int c = 0; c < 4; ++c)
#pragma unroll
        for (int k = 0; k < 9; ++k) {
            float t = xb[c * NN + tid + k * 256];
            v[c][k] = t; s += t; ss += t * t;
        }
#pragma unroll
    for (int o = 32; o > 0; o >>= 1) { s += __shfl_down(s, o); ss += __shfl_down(ss, o); }
    __shared__ float red[8];
    __shared__ float stats[2];
    int wid = tid >> 6;
    if ((tid & 63) == 0) { red[wid * 2] = s; red[wid * 2 + 1] = ss; }
    __syncthreads();
    if (tid == 0) {
        float S = 0.f, SS = 0.f;
        for (int i = 0; i < 4; ++i) { S += red[i * 2]; SS += red[i * 2 + 1]; }
        float mu = S * (1.f / 9216.f);
        float var = SS * (1.f / 9216.f) - mu * mu;
        stats[0] = mu;
        stats[1] = rsqrtf(var + 1e-5f);
    }
    __syncthreads();
    float mu = stats[0], rs = stats[1];
    float sc[4], bi[4];
#pragma unroll
    for (int c = 0; c < 4; ++c) {
        sc[c] = gw[g * 4 + c] * rs;
        bi[c] = gb[g * 4 + c] - mu * sc[c];
    }
#pragma unroll
    for (int k = 0; k < 9; ++k) {
        int n = tid + k * 256;
        ushort4 o;
        o.x = f2bf(v[0][k] * sc[0] + bi[0]);
        o.y = f2bf(v[1][k] * sc[1] + bi[1]);
        o.z = f2bf(v[2][k] * sc[2] + bi[2]);
        o.w = f2bf(v[3][k] * sc[3] + bi[3]);
        *(ushort4*)(xnT + ((size_t)b * NN + n) * CC + g * 4) = o;
    }
}

// ---------------- K2: QKV via MFMA (z=0: q+k, z=1: v) — 64-row blocks, 576 total ------
// grid (8, 36, 2): b = blockIdx.x (fastest) -> XCD b; 64-row n-chunk = blockIdx.y.
// Operand-swapped MFMAs (D rows = first arg) -> consecutive fast-axis elems per lane,
// all stores single ushort4. z=0: each wave owns 16 rows; z=1: block covers 4 nf.
// q: natural qT[b][n][c], pre-scaled. k: TILED kt2[b][n/32][c/32][slot][c&31],
// slot(n)=((n&4)<<2)+((n&24)>>1)+(n&3). v: TILED vt2[b][n/32][c/16][c&15][n&31].
__global__ __launch_bounds__(256) void qkv_kernel(
        const u16* __restrict__ xnT, const u16* __restrict__ w16,
        const float* __restrict__ bq, const float* __restrict__ bk,
        const float* __restrict__ bv,
        u16* __restrict__ qT, u16* __restrict__ kt2, u16* __restrict__ vt2) {
    int b = blockIdx.x, n0 = blockIdx.y * 64, z = blockIdx.z;
    int tid = threadIdx.x, lane = tid & 63, wvw = tid >> 6;
    int l15 = lane & 15, l4 = lane >> 4;
    const u16* xb = xnT + (size_t)b * NN * CC;

    if (z == 0) {
        const u16* w16q = w16;
        const u16* w16k = w16 + 16384;
        u16* kb = kt2 + (size_t)b * NN * CC;
        // each wave: 16 rows n = n0 + wvw*16 + l15
        s16x8 xa[4];
#pragma unroll
        for (int ks = 0; ks < 4; ++ks)
            xa[ks] = *(const s16x8*)(xb + (size_t)(n0 + wvw * 16 + l15) * CC + ks * 32 + l4 * 8);
        int chunk = blockIdx.y * 2 + (wvw >> 1);
        int n5 = (wvw & 1) * 16 + l15;
        int slot = ((n5 & 4) << 2) + ((n5 & 24) >> 1) + (n5 & 3);
        int n = n0 + wvw * 16 + l15;
#pragma unroll 2
        for (int nf = 0; nf < 8; ++nf) {
            f32x4 aq = {}, ak = {};
#pragma unroll
            for (int ks = 0; ks < 4; ++ks) {
                s16x8 fq = *(const s16x8*)(w16q + (nf * 16 + l15) * CC + ks * 32 + l4 * 8);
                s16x8 fk = *(const s16x8*)(w16k + (nf * 16 + l15) * CC + ks * 32 + l4 * 8);
                aq = MFMA(fq, xa[ks], aq);   // rows=co, cols=n
                ak = MFMA(fk, xa[ks], ak);
            }
            // lane: co = nf*16 + l4*4 + r (consecutive r) ; n fixed per lane
            int cob = nf * 16 + l4 * 4;
            float4 bq4 = *(const float4*)(bq + cob);
            float4 bk4 = *(const float4*)(bk + cob);
            ushort4 qo;
            qo.x = f2bf((aq[0] + bq4.x) * SCALE_L2E);
            qo.y = f2bf((aq[1] + bq4.y) * SCALE_L2E);
            qo.z = f2bf((aq[2] + bq4.z) * SCALE_L2E);
            qo.w = f2bf((aq[3] + bq4.w) * SCALE_L2E);
            *(ushort4*)(qT + ((size_t)b * NN + n) * CC + cob) = qo;
            ushort4 ko;
            ko.x = f2bf(ak[0] + bk4.x);
            ko.y = f2bf(ak[1] + bk4.y);
            ko.z = f2bf(ak[2] + bk4.z);
            ko.w = f2bf(ak[3] + bk4.w);
            *(ushort4*)(kb + (size_t)chunk * 4096 + (cob >> 5) * 1024 + slot * 32 + (cob & 31)) = ko;
        }
    } else {
        const u16* w16v = w16 + 2 * 16384;
        u16* vb = vt2 + (size_t)b * NN * CC;
        s16x8 wa[2][4];
#pragma unroll
        for (int mf = 0; mf < 2; ++mf)
#pragma unroll
            for (int ks = 0; ks < 4; ++ks)
                wa[mf][ks] = *(const s16x8*)(w16v + (wvw * 32 + mf * 16 + l15) * CC + ks * 32 + l4 * 8);
        // c fixed per (lane, mf) after the swap -> bias scalar per mf
        float bvl[2];
        bvl[0] = bv[wvw * 32 + l15];
        bvl[1] = bv[wvw * 32 + 16 + l15];
#pragma unroll 2
        for (int nf = 0; nf < 4; ++nf) {
            f32x4 av[2] = {};
#pragma unroll
            for (int ks = 0; ks < 4; ++ks) {
                s16x8 xf = *(const s16x8*)(xb + (size_t)(n0 + nf * 16 + l15) * CC + ks * 32 + l4 * 8);
#pragma unroll
                for (int mf = 0; mf < 2; ++mf) av[mf] = MFMA(xf, wa[mf][ks], av[mf]);  // rows=n, cols=c
            }
            // lane: n = n0 + nf*16 + l4*4 + r (consecutive r) ; c = wvw*32 + mf*16 + l15
            int chunk = blockIdx.y * 2 + (nf >> 1);
            int nlo = (nf & 1) * 16 + l4 * 4;
#pragma unroll
            for (int mf = 0; mf < 2; ++mf) {
                ushort4 vo;
                vo.x = f2bf(av[mf][0] + bvl[mf]);
                vo.y = f2bf(av[mf][1] + bvl[mf]);
                vo.z = f2bf(av[mf][2] + bvl[mf]);
                vo.w = f2bf(av[mf][3] + bvl[mf]);
                *(ushort4*)(vb + (size_t)chunk * 4096 + (wvw * 2 + mf) * 512 + l15 * 32 + nlo) = vo;
            }
        }
    }
}

// ---------------- K3: attention — K reg double-buffer + b->XCD locality (R3 proven) ----
// grid (8, 48, 3): b = blockIdx.x (fastest) -> all 144 blocks of batch b on XCD b.
// S = mfma(K,Q): sf[mf][hf] reg r at lane(l4,l15) = S[slot mf*16+4l4+r][h=hf*16+l15];
// slot permutation makes {sf[0][hf], sf[1][hf]} the PV B-frag directly (k = n = 8*l4+j).
// PV = mfma(V,P): cacc[cf][hf] reg r = ctx[c = cf*16+4*l4+r][h = hf*16+l15].
// Pipeline: V(t) issued at top; K(t+1) issued right after S(t). Ping-pong kfA/kfB via
// macro text expansion — all array indices compile-time constant, nothing address-taken.
#define TILE_BODY(T, KFC, KFN) { \
    const u16* cv = vb + (size_t)((T) * 4 + wvw) * 4096; \
    s16x8 vf[8]; \
    _Pragma("unroll") \
    for (int cf = 0; cf < 8; ++cf) \
        vf[cf] = *(const s16x8*)(cv + cf * 512 + l15 * 32 + l4 * 8); \
    f32x4 sf[2][3] = {}; \
    __builtin_amdgcn_s_setprio(1); \
    _Pragma("unroll") \
    for (int ks = 0; ks < 4; ++ks) \
        _Pragma("unroll") \
        for (int mf = 0; mf < 2; ++mf) \
            _Pragma("unroll") \
            for (int hf = 0; hf < 3; ++hf) \
                sf[mf][hf] = MFMA(KFC[mf][ks], qf[hf][ks], sf[mf][hf]); \
    __builtin_amdgcn_s_setprio(0); \
    { \
        int tn_ = ((T) + 1 < 18) ? (T) + 1 : 0; \
        const u16* cbn_ = kb + (size_t)(tn_ * 4 + wvw) * 4096; \
        _Pragma("unroll") \
        for (int mf = 0; mf < 2; ++mf) \
            _Pragma("unroll") \
            for (int ks = 0; ks < 4; ++ks) \
                KFN[mf][ks] = *(const s16x8*)(cbn_ + ks * 1024 + (mf * 16 + l15) * 32 + l4 * 8); \
    } \
    float p[2][3][4]; \
    _Pragma("unroll") \
    for (int mf = 0; mf < 2; ++mf) \
        _Pragma("unroll") \
        for (int hf = 0; hf < 3; ++hf) \
            _Pragma("unroll") \
            for (int r = 0; r < 4; ++r) p[mf][hf][r] = __builtin_amdgcn_exp2f(sf[mf][hf][r]); \
    float den[2][4]; \
    _Pragma("unroll") \
    for (int mf = 0; mf < 2; ++mf) \
        _Pragma("unroll") \
        for (int r = 0; r < 4; ++r) \
            den[mf][r] = p[mf][0][r] + p[mf][1][r] + p[mf][2][r]; \
    _Pragma("unroll") \
    for (int mf = 0; mf < 2; ++mf) \
        _Pragma("unroll") \
        for (int r = 0; r < 4; ++r) { \
            DPP_ROR_ADD(den[mf][r], 1); \
            DPP_ROR_ADD(den[mf][r], 2); \
            DPP_ROR_ADD(den[mf][r], 4); \
            DPP_ROR_ADD(den[mf][r], 8); \
        } \
    float rd[2][4]; \
    _Pragma("unroll") \
    for (int mf = 0; mf < 2; ++mf) \
        _Pragma("unroll") \
        for (int r = 0; r < 4; ++r) rd[mf][r] = __builtin_amdgcn_rcpf(den[mf][r]); \
    s16x8 pbf[3]; \
    _Pragma("unroll") \
    for (int hf = 0; hf < 3; ++hf) { \
        unsigned u0, u1, u2, u3; \
        float a0 = p[0][hf][0] * rd[0][0], a1 = p[0][hf][1] * rd[0][1]; \
        float a2 = p[0][hf][2] * rd[0][2], a3 = p[0][hf][3] * rd[0][3]; \
        float a4 = p[1][hf][0] * rd[1][0], a5 = p[1][hf][1] * rd[1][1]; \
        float a6 = p[1][hf][2] * rd[1][2], a7 = p[1][hf][3] * rd[1][3]; \
        asm("v_cvt_pk_bf16_f32 %0, %1, %2" : "=v"(u0) : "v"(a0), "v"(a1)); \
        asm("v_cvt_pk_bf16_f32 %0, %1, %2" : "=v"(u1) : "v"(a2), "v"(a3)); \
        asm("v_cvt_pk_bf16_f32 %0, %1, %2" : "=v"(u2) : "v"(a4), "v"(a5)); \
        asm("v_cvt_pk_bf16_f32 %0, %1, %2" : "=v"(u3) : "v"(a6), "v"(a7)); \
        i32x4 bb2 = { (int)u0, (int)u1, (int)u2, (int)u3 }; \
        pbf[hf] = __builtin_bit_cast(s16x8, bb2); \
    } \
    __builtin_amdgcn_s_setprio(1); \
    _Pragma("unroll") \
    for (int cf = 0; cf < 8; ++cf) \
        _Pragma("unroll") \
        for (int hf = 0; hf < 3; ++hf) \
            cacc[cf][hf] = MFMA(vf[cf], pbf[hf], cacc[cf][hf]); \
    __builtin_amdgcn_s_setprio(0); \
}

__global__ __launch_bounds__(256, 2) void attn_kernel(
        const u16* __restrict__ qT, const u16* __restrict__ kt2,
        const u16* __restrict__ vt2, u16* __restrict__ part) {
    int b = blockIdx.x, w = blockIdx.y, sp = blockIdx.z;
    int tid = threadIdx.x, lane = tid & 63, wvw = tid >> 6;
    int l15 = lane & 15, l4 = lane >> 4;
    __shared__ float red[4 * 48 * 36];   // [q][h][c&31 + pad4]

    const u16* qb = qT + (size_t)b * NN * CC;
    const u16* kb = kt2 + (size_t)b * NN * CC;
    const u16* vb = vt2 + (size_t)b * NN * CC;

    // Q B-frags hoisted: cols h = hf*16 + l15 at fixed w
    s16x8 qf[3][4];
#pragma unroll
    for (int hf = 0; hf < 3; ++hf)
#pragma unroll
        for (int ks = 0; ks < 4; ++ks)
            qf[hf][ks] = *(const s16x8*)(qb + (size_t)((hf * 16 + l15) * WW + w) * CC + ks * 32 + l4 * 8);

    f32x4 cacc[8][3] = {};   // reg r: c = cf*16+4*l4+r ; h = hf*16+l15

    const int tbase = sp * TILES_PER;

    // prologue: preload K(tbase)
    s16x8 kfA[2][4], kfB[2][4];
    {
        const u16* cb = kb + (size_t)(tbase * 4 + wvw) * 4096;
#pragma unroll
        for (int mf = 0; mf < 2; ++mf)
#pragma unroll
            for (int ks = 0; ks < 4; ++ks)
                kfA[mf][ks] = *(const s16x8*)(cb + ks * 1024 + (mf * 16 + l15) * 32 + l4 * 8);
    }

#pragma unroll 1
    for (int tt = 0; tt < TILES_PER; tt += 2) {
        int t0 = tbase + tt;
        TILE_BODY(t0, kfA, kfB)
        int t1 = tbase + tt + 1;
        TILE_BODY(t1, kfB, kfA)
    }

    // ---- 4-stage round-robin quadrant reduce (27KB buffer) ----
    // stage s: wave v handles c-quadrant q = (v+s)&3 (cf = 2q, 2q+1)
#pragma unroll
    for (int s = 0; s < 4; ++s) {
        if (s) __syncthreads();
#pragma unroll
        for (int q = 0; q < 4; ++q) {
            if (((q - wvw) & 3) == s) {
#pragma unroll
                for (int i = 0; i < 2; ++i) {
                    int cf = 2 * q + i;
#pragma unroll
                    for (int hf = 0; hf < 3; ++hf) {
                        int addr = q * 1728 + (hf * 16 + l15) * 36 + i * 16 + 4 * l4;
                        f32x4* pp = (f32x4*)&red[addr];
                        if (s == 0) *pp = cacc[cf][hf];
                        else { f32x4 tv = *pp; tv += cacc[cf][hf]; *pp = tv; }
                    }
                }
            }
        }
    }
    __syncthreads();
    // final store: wave v owns quadrant v; lane (l4 = h-sub, l15 = c-pair)
    u16* po = part + (size_t)(b * NSPLIT + sp) * NN * CC;
#pragma unroll
    for (int pass = 0; pass < 12; ++pass) {
        int h = pass * 4 + l4;
        int c = wvw * 32 + l15 * 2;
        float2 v2 = *(float2*)&red[wvw * 1728 + h * 36 + l15 * 2];
        unsigned pk;
        asm("v_cvt_pk_bf16_f32 %0, %1, %2" : "=v"(pk) : "v"(v2.x), "v"(v2.y));
        *(unsigned*)(po + (size_t)(h * WW + w) * CC + c) = pk;
    }
}

// ---------------- K4: partial-reduce + out proj + bias + residual — 32-row blocks ------
// grid (8, 72): b = blockIdx.x -> XCD b. Block covers 32 n-rows; each wave owns one
// co-quadrant (mf = 2*wvw, 2*wvw+1). All 4 waves read the SAME part rows -> L1 broadcast.
__global__ __launch_bounds__(256) void out_kernel(
        const u16* __restrict__ part, const u16* __restrict__ w16o,
        const float* __restrict__ bo, const float* __restrict__ x,
        float* __restrict__ out) {
    int b = blockIdx.x, n0 = blockIdx.y * 32;
    int tid = threadIdx.x, lane = tid & 63, wvw = tid >> 6;
    int l15 = lane & 15, l4 = lane >> 4;
    const u16* pb = part + (size_t)b * NSPLIT * NN * CC;
    s16x8 bfr[2][4];
#pragma unroll
    for (int nf = 0; nf < 2; ++nf)
#pragma unroll
        for (int ks = 0; ks < 4; ++ks) {
            size_t off = (size_t)(n0 + nf * 16 + l15) * CC + ks * 32 + l4 * 8;
            s16x8 v0 = *(const s16x8*)(pb + off);
            s16x8 v1 = *(const s16x8*)(pb + (size_t)NN * CC + off);
            s16x8 v2 = *(const s16x8*)(pb + (size_t)2 * NN * CC + off);
            s16x8 o;
#pragma unroll
            for (int j = 0; j < 8; ++j)
                o[j] = (short)f2bf(bf2f((u16)v0[j]) + bf2f((u16)v1[j]) + bf2f((u16)v2[j]));
            bfr[nf][ks] = o;
        }
#pragma unroll
    for (int mi = 0; mi < 2; ++mi) {
        int mf = wvw * 2 + mi;
        s16x8 af[4];
#pragma unroll
        for (int ks = 0; ks < 4; ++ks)
            af[ks] = *(const s16x8*)(w16o + (mf * 16 + l15) * CC + ks * 32 + l4 * 8);
        f32x4 acc[2] = {};
#pragma unroll
        for (int ks = 0; ks < 4; ++ks)
#pragma unroll
            for (int nf = 0; nf < 2; ++nf)
                acc[nf] = MFMA(af[ks], bfr[nf][ks], acc[nf]);
#pragma unroll
        for (int nf = 0; nf < 2; ++nf)
#pragma unroll
            for (int r = 0; r < 4; ++r) {
                int co = mf * 16 + l4 * 4 + r;
                int n = n0 + nf * 16 + l15;
                size_t idx = ((size_t)b * CC + co) * NN + n;
                out[idx] = acc[nf][r] + bo[co] + x[idx];
            }
    }
}

extern "C" void kernel_launch(void* const* d_in, const int* in_sizes, int n_in,
                              void* d_out, int out_size, void* d_ws, size_t ws_size,
                              hipStream_t stream) {
    const float* x  = (const float*)d_in[0];
    const float* gw = (const float*)d_in[1];
    const float* gb = (const float*)d_in[2];
    const float* wq = (const float*)d_in[3];
    const float* bq = (const float*)d_in[4];
    const float* wk = (const float*)d_in[5];
    const float* bk = (const float*)d_in[6];
    const float* wv_ = (const float*)d_in[7];
    const float* bv = (const float*)d_in[8];
    const float* wo = (const float*)d_in[9];
    const float* bo = (const float*)d_in[10];

    u16* ws   = (u16*)d_ws;
    u16* xnT  = ws;
    u16* qT   = ws + (size_t)SZ_MAP;
    u16* kt2  = ws + (size_t)2 * SZ_MAP;
    u16* vt2  = ws + (size_t)3 * SZ_MAP;
    u16* part = ws + (size_t)4 * SZ_MAP;             // NSPLIT * SZ_MAP bf16
    u16* w16  = ws + (size_t)(4 + NSPLIT) * SZ_MAP;  // 4*16384 bf16
    float* out = (float*)d_out;

    gnprep_kernel<<<512, 256, 0, stream>>>(x, gw, gb, xnT, wq, wk, wv_, wo, w16);
    qkv_kernel<<<dim3(8, 36, 2), 256, 0, stream>>>(xnT, w16, bq, bk, bv, qT, kt2, vt2);
    attn_kernel<<<dim3(8, WW, NSPLIT), 256, 0, stream>>>(qT, kt2, vt2, part);
    out_kernel<<<dim3(8, 72), 256, 0, stream>>>(part, w16 + 3 * 16384, bo, x, out);
}

// Round 8
// 77.063 us; speedup vs baseline: 1.1341x; 1.1341x over previous
//
#include <hip/hip_runtime.h>
#include <hip/hip_bf16.h>

typedef short s16x8 __attribute__((ext_vector_type(8)));
typedef float f32x4 __attribute__((ext_vector_type(4)));
typedef int   i32x4 __attribute__((ext_vector_type(4)));
typedef unsigned short u16;

#define BB 8
#define CC 128
#define HH 48
#define WW 48
#define NN 2304
#define SCALE_L2E 0.12751744f          // log2(e)/sqrt(128)
#define SZ_MAP (BB*CC*NN)              // 2359296 elements
#define NSPLIT 2
#define TILES_PER (18/NSPLIT)

__device__ inline u16 f2bf(float f) {
    unsigned u = __builtin_bit_cast(unsigned, f);
    u = (u + 0x7FFFu + ((u >> 16) & 1u)) >> 16;
    return (u16)u;
}
__device__ inline float bf2f(u16 h) {
    unsigned u = ((unsigned)h) << 16;
    return __builtin_bit_cast(float, u);
}

#define MFMA(a, b, c) __builtin_amdgcn_mfma_f32_16x16x32_bf16(a, b, c, 0, 0, 0)
// DPP rotate-add within each 16-lane row (VALU pipe, no LDS traffic)
#define DPP_ROR_ADD(x, N) { \
    int yi_ = __builtin_amdgcn_update_dpp(0, __builtin_bit_cast(int, x), 0x120 | (N), 0xf, 0xf, true); \
    x += __builtin_bit_cast(float, yi_); }

// ---------------- K1: GroupNorm -> xnT16[b][n][c]  +  weight cast (fused) ----------------
// b = blockIdx.x & 7 so all blocks of batch b land on XCD b (blockid % 8 == b).
__global__ __launch_bounds__(256) void gnprep_kernel(
        const float* __restrict__ x, const float* __restrict__ gw,
        const float* __restrict__ gb, u16* __restrict__ xnT,
        const float* __restrict__ wq, const float* __restrict__ wk,
        const float* __restrict__ wv_, const float* __restrict__ wo,
        u16* __restrict__ w16) {
    int tid = threadIdx.x;
    if (blockIdx.x >= 256) {
        int i = (blockIdx.x - 256) * 256 + tid;   // 0..65535
        int m = i >> 14, r = i & 16383;
        const float* src = (m == 0) ? wq : (m == 1) ? wk : (m == 2) ? wv_ : wo;
        w16[i] = f2bf(src[r]);
        return;
    }
    int b = blockIdx.x & 7, g = blockIdx.x >> 3;
    const float* xb = x + ((size_t)b * CC + g * 4) * NN;
    float v[4][9];
    float s = 0.f, ss = 0.f;
#pragma unroll
    for (int c = 0; c < 4; ++c)
#pragma unroll
        for (int k = 0; k < 9; ++k) {
            float t = xb[c * NN + tid + k * 256];
            v[c][k] = t; s += t; ss += t * t;
        }
#pragma unroll
    for (int o = 32; o > 0; o >>= 1) { s += __shfl_down(s, o); ss += __shfl_down(ss, o); }
    __shared__ float red[8];
    __shared__ float stats[2];
    int wid = tid >> 6;
    if ((tid & 63) == 0) { red[wid * 2] = s; red[wid * 2 + 1] = ss; }
    __syncthreads();
    if (tid == 0) {
        float S = 0.f, SS = 0.f;
        for (int i = 0; i < 4; ++i) { S += red[i * 2]; SS += red[i * 2 + 1]; }
        float mu = S * (1.f / 9216.f);
        float var = SS * (1.f / 9216.f) - mu * mu;
        stats[0] = mu;
        stats[1] = rsqrtf(var + 1e-5f);
    }
    __syncthreads();
    float mu = stats[0], rs = stats[1];
    float sc[4], bi[4];
#pragma unroll
    for (int c = 0; c < 4; ++c) {
        sc[c] = gw[g * 4 + c] * rs;
        bi[c] = gb[g * 4 + c] - mu * sc[c];
    }
#pragma unroll
    for (int k = 0; k < 9; ++k) {
        int n = tid + k * 256;
        ushort4 o;
        o.x = f2bf(v[0][k] * sc[0] + bi[0]);
        o.y = f2bf(v[1][k] * sc[1] + bi[1]);
        o.z = f2bf(v[2][k] * sc[2] + bi[2]);
        o.w = f2bf(v[3][k] * sc[3] + bi[3]);
        *(ushort4*)(xnT + ((size_t)b * NN + n) * CC + g * 4) = o;
    }
}

// ---------------- K2: QKV via MFMA (z=0: q+k, z=1: v) — coalesced ushort4 stores ------
// grid (8, 18, 2): b = blockIdx.x (fastest) -> XCD b; n-chunk = blockIdx.y. (R6 proven)
// Operand-swapped MFMAs: D rows = first-arg rows, so each lane holds 4 consecutive
// fast-axis elements of every output layout -> all stores single ushort4.
// q: natural qT[b][n][c], pre-scaled. k: TILED kt2[b][n/32][c/32][slot][c&31],
// slot(n)=((n&4)<<2)+((n&24)>>1)+(n&3). v: TILED vt2[b][n/32][c/16][c&15][n&31].
__global__ __launch_bounds__(256) void qkv_kernel(
        const u16* __restrict__ xnT, const u16* __restrict__ w16,
        const float* __restrict__ bq, const float* __restrict__ bk,
        const float* __restrict__ bv,
        u16* __restrict__ qT, u16* __restrict__ kt2, u16* __restrict__ vt2) {
    int b = blockIdx.x, n0 = blockIdx.y * 128, z = blockIdx.z;
    int tid = threadIdx.x, lane = tid & 63, wvw = tid >> 6;
    int l15 = lane & 15, l4 = lane >> 4;
    const u16* xb = xnT + (size_t)b * NN * CC;

    if (z == 0) {
        const u16* w16q = w16;
        const u16* w16k = w16 + 16384;
        u16* kb = kt2 + (size_t)b * NN * CC;
        s16x8 xa[2][4];
#pragma unroll
        for (int mf = 0; mf < 2; ++mf)
#pragma unroll
            for (int ks = 0; ks < 4; ++ks)
                xa[mf][ks] = *(const s16x8*)(xb + (size_t)(n0 + wvw * 32 + mf * 16 + l15) * CC + ks * 32 + l4 * 8);
        int chunk = blockIdx.y * 4 + wvw;
#pragma unroll 2
        for (int nf = 0; nf < 8; ++nf) {
            f32x4 aq[2] = {}, ak[2] = {};
#pragma unroll
            for (int ks = 0; ks < 4; ++ks) {
                s16x8 fq = *(const s16x8*)(w16q + (nf * 16 + l15) * CC + ks * 32 + l4 * 8);
                s16x8 fk = *(const s16x8*)(w16k + (nf * 16 + l15) * CC + ks * 32 + l4 * 8);
#pragma unroll
                for (int mf = 0; mf < 2; ++mf) {
                    aq[mf] = MFMA(fq, xa[mf][ks], aq[mf]);   // rows=co, cols=n
                    ak[mf] = MFMA(fk, xa[mf][ks], ak[mf]);
                }
            }
            int cob = nf * 16 + l4 * 4;
            float4 bq4 = *(const float4*)(bq + cob);
            float4 bk4 = *(const float4*)(bk + cob);
#pragma unroll
            for (int mf = 0; mf < 2; ++mf) {
                int n = n0 + wvw * 32 + mf * 16 + l15;
                ushort4 qo;
                qo.x = f2bf((aq[mf][0] + bq4.x) * SCALE_L2E);
                qo.y = f2bf((aq[mf][1] + bq4.y) * SCALE_L2E);
                qo.z = f2bf((aq[mf][2] + bq4.z) * SCALE_L2E);
                qo.w = f2bf((aq[mf][3] + bq4.w) * SCALE_L2E);
                *(ushort4*)(qT + ((size_t)b * NN + n) * CC + cob) = qo;
                int n5 = mf * 16 + l15;
                int slot = ((n5 & 4) << 2) + ((n5 & 24) >> 1) + (n5 & 3);
                ushort4 ko;
                ko.x = f2bf(ak[mf][0] + bk4.x);
                ko.y = f2bf(ak[mf][1] + bk4.y);
                ko.z = f2bf(ak[mf][2] + bk4.z);
                ko.w = f2bf(ak[mf][3] + bk4.w);
                *(ushort4*)(kb + (size_t)chunk * 4096 + (cob >> 5) * 1024 + slot * 32 + (cob & 31)) = ko;
            }
        }
    } else {
        const u16* w16v = w16 + 2 * 16384;
        u16* vb = vt2 + (size_t)b * NN * CC;
        s16x8 wa[2][4];
#pragma unroll
        for (int mf = 0; mf < 2; ++mf)
#pragma unroll
            for (int ks = 0; ks < 4; ++ks)
                wa[mf][ks] = *(const s16x8*)(w16v + (wvw * 32 + mf * 16 + l15) * CC + ks * 32 + l4 * 8);
        float bvl[2];
        bvl[0] = bv[wvw * 32 + l15];
        bvl[1] = bv[wvw * 32 + 16 + l15];
#pragma unroll 2
        for (int nf = 0; nf < 8; ++nf) {
            f32x4 av[2] = {};
#pragma unroll
            for (int ks = 0; ks < 4; ++ks) {
                s16x8 xf = *(const s16x8*)(xb + (size_t)(n0 + nf * 16 + l15) * CC + ks * 32 + l4 * 8);
#pragma unroll
                for (int mf = 0; mf < 2; ++mf) av[mf] = MFMA(xf, wa[mf][ks], av[mf]);  // rows=n, cols=c
            }
            int chunk = blockIdx.y * 4 + (nf >> 1);
            int nlo = (nf & 1) * 16 + l4 * 4;
#pragma unroll
            for (int mf = 0; mf < 2; ++mf) {
                ushort4 vo;
                vo.x = f2bf(av[mf][0] + bvl[mf]);
                vo.y = f2bf(av[mf][1] + bvl[mf]);
                vo.z = f2bf(av[mf][2] + bvl[mf]);
                vo.w = f2bf(av[mf][3] + bvl[mf]);
                *(ushort4*)(vb + (size_t)chunk * 4096 + (wvw * 2 + mf) * 512 + l15 * 32 + nlo) = vo;
            }
        }
    }
}

// ---------------- K3: attention — register diet for 3 waves/SIMD ----------------------
// grid (8, 48, 2): 768 blocks = exactly 1 round at 3 blocks/CU. b fastest -> XCD b.
// Diet: Q lives in LDS (swizzled; saves 48 VGPR), K streamed per-ks (8-reg window,
// saves 56 vs double-buffer), V streamed per-cf. Target <=170 unified regs/wave.
// Q LDS swizzle: 16B chunk m = ks*4+l4 stored at m^(h&7) -> wave b128 reads land
// 8 lanes per 4-bank group (the b128 optimum; unswizzled was 16-way on one group).
// S = mfma(K,Q): sf[mf][hf] reg r = S[slot mf*16+4l4+r][h=hf*16+l15]; slot perm makes
// {sf[0][hf], sf[1][hf]} the PV B-frag directly. PV = mfma(V,P) into cacc[cf][hf].
__global__ __launch_bounds__(256, 3) void attn_kernel(
        const u16* __restrict__ qT, const u16* __restrict__ kt2,
        const u16* __restrict__ vt2, u16* __restrict__ part) {
    int b = blockIdx.x, w = blockIdx.y, sp = blockIdx.z;
    int tid = threadIdx.x, lane = tid & 63, wvw = tid >> 6;
    int l15 = lane & 15, l4 = lane >> 4;
    __shared__ float red[4 * 48 * 36];   // 27648 B reduce buffer
    __shared__ u16 qlds[48 * 128];       // 12288 B swizzled Q

    const u16* qb = qT + (size_t)b * NN * CC;
    const u16* kb = kt2 + (size_t)b * NN * CC;
    const u16* vb = vt2 + (size_t)b * NN * CC;

    // stage Q into LDS once: wave wvw writes (hf,ks) pairs with (hf*4+ks)%4 == wvw
#pragma unroll
    for (int pp = 0; pp < 3; ++pp) {
        int pid = pp * 4 + wvw;          // 0..11
        int hf = pid >> 2, ks = pid & 3;
        s16x8 q = *(const s16x8*)(qb + (size_t)((hf * 16 + l15) * WW + w) * CC + ks * 32 + l4 * 8);
        int m = (ks * 4 + l4) ^ (l15 & 7);
        *(s16x8*)(qlds + (hf * 16 + l15) * 128 + m * 8) = q;
    }
    __syncthreads();

    f32x4 cacc[8][3] = {};   // reg r: c = cf*16+4*l4+r ; h = hf*16+l15

    const int tbase = sp * TILES_PER;
#pragma unroll 1
    for (int t = tbase; t < tbase + TILES_PER; ++t) {
        asm volatile("" ::: "memory");   // force per-tile LDS Q re-reads (no reg hoist)
        const u16* cb = kb + (size_t)(t * 4 + wvw) * 4096;
        const u16* cv = vb + (size_t)(t * 4 + wvw) * 4096;
        // S = K·Q, K streamed per-ks (contiguous 1KB wave loads), Q from LDS
        f32x4 sf[2][3] = {};
        __builtin_amdgcn_s_setprio(1);
#pragma unroll
        for (int ks = 0; ks < 4; ++ks) {
            s16x8 kf0 = *(const s16x8*)(cb + ks * 1024 + l15 * 32 + l4 * 8);
            s16x8 kf1 = *(const s16x8*)(cb + ks * 1024 + (16 + l15) * 32 + l4 * 8);
#pragma unroll
            for (int hf = 0; hf < 3; ++hf) {
                s16x8 q = *(const s16x8*)(qlds + (hf * 16 + l15) * 128
                                          + (((ks * 4 + l4) ^ (l15 & 7)) * 8));
                sf[0][hf] = MFMA(kf0, q, sf[0][hf]);
                sf[1][hf] = MFMA(kf1, q, sf[1][hf]);
            }
        }
        __builtin_amdgcn_s_setprio(0);
        // softmax over h: exp2 (log2e folded into q), per-slot den, DPP rotate-reduce
        float pe[2][3][4];
#pragma unroll
        for (int mf = 0; mf < 2; ++mf)
#pragma unroll
            for (int hf = 0; hf < 3; ++hf)
#pragma unroll
                for (int r = 0; r < 4; ++r) pe[mf][hf][r] = __builtin_amdgcn_exp2f(sf[mf][hf][r]);
        float den[2][4];
#pragma unroll
        for (int mf = 0; mf < 2; ++mf)
#pragma unroll
            for (int r = 0; r < 4; ++r)
                den[mf][r] = pe[mf][0][r] + pe[mf][1][r] + pe[mf][2][r];
#pragma unroll
        for (int mf = 0; mf < 2; ++mf)
#pragma unroll
            for (int r = 0; r < 4; ++r) {
                DPP_ROR_ADD(den[mf][r], 1);
                DPP_ROR_ADD(den[mf][r], 2);
                DPP_ROR_ADD(den[mf][r], 4);
                DPP_ROR_ADD(den[mf][r], 8);
            }
        float rd[2][4];
#pragma unroll
        for (int mf = 0; mf < 2; ++mf)
#pragma unroll
            for (int r = 0; r < 4; ++r) rd[mf][r] = __builtin_amdgcn_rcpf(den[mf][r]);
        // P B-frags directly from sf registers (slot permutation pre-applied to K)
        s16x8 pbf[3];
#pragma unroll
        for (int hf = 0; hf < 3; ++hf) {
            unsigned u0, u1, u2, u3;
            float a0 = pe[0][hf][0] * rd[0][0], a1 = pe[0][hf][1] * rd[0][1];
            float a2 = pe[0][hf][2] * rd[0][2], a3 = pe[0][hf][3] * rd[0][3];
            float a4 = pe[1][hf][0] * rd[1][0], a5 = pe[1][hf][1] * rd[1][1];
            float a6 = pe[1][hf][2] * rd[1][2], a7 = pe[1][hf][3] * rd[1][3];
            asm("v_cvt_pk_bf16_f32 %0, %1, %2" : "=v"(u0) : "v"(a0), "v"(a1));
            asm("v_cvt_pk_bf16_f32 %0, %1, %2" : "=v"(u1) : "v"(a2), "v"(a3));
            asm("v_cvt_pk_bf16_f32 %0, %1, %2" : "=v"(u2) : "v"(a4), "v"(a5));
            asm("v_cvt_pk_bf16_f32 %0, %1, %2" : "=v"(u3) : "v"(a6), "v"(a7));
            i32x4 bb2 = { (int)u0, (int)u1, (int)u2, (int)u3 };
            pbf[hf] = __builtin_bit_cast(s16x8, bb2);
        }
        // PV, V streamed per-cf (contiguous 1KB wave loads)
        __builtin_amdgcn_s_setprio(1);
#pragma unroll
        for (int cf = 0; cf < 8; ++cf) {
            s16x8 vf = *(const s16x8*)(cv + cf * 512 + l15 * 32 + l4 * 8);
#pragma unroll
            for (int hf = 0; hf < 3; ++hf)
                cacc[cf][hf] = MFMA(vf, pbf[hf], cacc[cf][hf]);
        }
        __builtin_amdgcn_s_setprio(0);
    }

    // ---- 4-stage round-robin quadrant reduce (27KB buffer) ----
#pragma unroll
    for (int s = 0; s < 4; ++s) {
        if (s) __syncthreads();
#pragma unroll
        for (int q = 0; q < 4; ++q) {
            if (((q - wvw) & 3) == s) {
#pragma unroll
                for (int i = 0; i < 2; ++i) {
                    int cf = 2 * q + i;
#pragma unroll
                    for (int hf = 0; hf < 3; ++hf) {
                        int addr = q * 1728 + (hf * 16 + l15) * 36 + i * 16 + 4 * l4;
                        f32x4* pp = (f32x4*)&red[addr];
                        if (s == 0) *pp = cacc[cf][hf];
                        else { f32x4 tv = *pp; tv += cacc[cf][hf]; *pp = tv; }
                    }
                }
            }
        }
    }
    __syncthreads();
    // final store: wave v owns quadrant v; lane (l4 = h-sub, l15 = c-pair)
    u16* po = part + (size_t)(b * NSPLIT + sp) * NN * CC;
#pragma unroll
    for (int pass = 0; pass < 12; ++pass) {
        int h = pass * 4 + l4;
        int c = wvw * 32 + l15 * 2;
        float2 v2 = *(float2*)&red[wvw * 1728 + h * 36 + l15 * 2];
        unsigned pk;
        asm("v_cvt_pk_bf16_f32 %0, %1, %2" : "=v"(pk) : "v"(v2.x), "v"(v2.y));
        *(unsigned*)(po + (size_t)(h * WW + w) * CC + c) = pk;
    }
}

// ---------------- K4: partial-reduce (2) + out proj + bias + residual ----------------
// grid (8, 18): b = blockIdx.x -> XCD b; part[b] read from same-XCD L2.
__global__ __launch_bounds__(256) void out_kernel(
        const u16* __restrict__ part, const u16* __restrict__ w16o,
        const float* __restrict__ bo, const float* __restrict__ x,
        float* __restrict__ out) {
    int b = blockIdx.x, n0 = blockIdx.y * 128;
    int tid = threadIdx.x, lane = tid & 63, wvw = tid >> 6;
    int l15 = lane & 15, l4 = lane >> 4;
    const u16* pb = part + (size_t)b * NSPLIT * NN * CC;
    s16x8 bfr[2][4];
#pragma unroll
    for (int nf = 0; nf < 2; ++nf)
#pragma unroll
        for (int ks = 0; ks < 4; ++ks) {
            size_t off = (size_t)(n0 + wvw * 32 + nf * 16 + l15) * CC + ks * 32 + l4 * 8;
            s16x8 v0 = *(const s16x8*)(pb + off);
            s16x8 v1 = *(const s16x8*)(pb + (size_t)NN * CC + off);
            s16x8 o;
#pragma unroll
            for (int j = 0; j < 8; ++j)
                o[j] = (short)f2bf(bf2f((u16)v0[j]) + bf2f((u16)v1[j]));
            bfr[nf][ks] = o;
        }
#pragma unroll 2
    for (int mf = 0; mf < 8; ++mf) {
        s16x8 af[4];
#pragma unroll
        for (int ks = 0; ks < 4; ++ks)
            af[ks] = *(const s16x8*)(w16o + (mf * 16 + l15) * CC + ks * 32 + l4 * 8);
        f32x4 acc[2] = {};
#pragma unroll
        for (int ks = 0; ks < 4; ++ks)
#pragma unroll
            for (int nf = 0; nf < 2; ++nf)
                acc[nf] = MFMA(af[ks], bfr[nf][ks], acc[nf]);
#pragma unroll
        for (int nf = 0; nf < 2; ++nf)
#pragma unroll
            for (int r = 0; r < 4; ++r) {
                int co = mf * 16 + l4 * 4 + r;
                int n = n0 + wvw * 32 + nf * 16 + l15;
                size_t idx = ((size_t)b * CC + co) * NN + n;
                out[idx] = acc[nf][r] + bo[co] + x[idx];
            }
    }
}

extern "C" void kernel_launch(void* const* d_in, const int* in_sizes, int n_in,
                              void* d_out, int out_size, void* d_ws, size_t ws_size,
                              hipStream_t stream) {
    const float* x  = (const float*)d_in[0];
    const float* gw = (const float*)d_in[1];
    const float* gb = (const float*)d_in[2];
    const float* wq = (const float*)d_in[3];
    const float* bq = (const float*)d_in[4];
    const float* wk = (const float*)d_in[5];
    const float* bk = (const float*)d_in[6];
    const float* wv_ = (const float*)d_in[7];
    const float* bv = (const float*)d_in[8];
    const float* wo = (const float*)d_in[9];
    const float* bo = (const float*)d_in[10];

    u16* ws   = (u16*)d_ws;
    u16* xnT  = ws;
    u16* qT   = ws + (size_t)SZ_MAP;
    u16* kt2  = ws + (size_t)2 * SZ_MAP;
    u16* vt2  = ws + (size_t)3 * SZ_MAP;
    u16* part = ws + (size_t)4 * SZ_MAP;             // NSPLIT * SZ_MAP bf16
    u16* w16  = ws + (size_t)(4 + NSPLIT) * SZ_MAP;  // 4*16384 bf16
    float* out = (float*)d_out;

    gnprep_kernel<<<512, 256, 0, stream>>>(x, gw, gb, xnT, wq, wk, wv_, wo, w16);
    qkv_kernel<<<dim3(8, 18, 2), 256, 0, stream>>>(xnT, w16, bq, bk, bv, qT, kt2, vt2);
    attn_kernel<<<dim3(8, WW, NSPLIT), 256, 0, stream>>>(qT, kt2, vt2, part);
    out_kernel<<<dim3(8, 18), 256, 0, stream>>>(part, w16 + 3 * 16384, bo, x, out);
}

// Round 9
// 70.402 us; speedup vs baseline: 1.2414x; 1.0946x over previous
//
#include <hip/hip_runtime.h>
#include <hip/hip_bf16.h>

typedef short s16x8 __attribute__((ext_vector_type(8)));
typedef float f32x4 __attribute__((ext_vector_type(4)));
typedef int   i32x4 __attribute__((ext_vector_type(4)));
typedef unsigned short u16;

#define BB 8
#define CC 128
#define HH 48
#define WW 48
#define NN 2304
#define SCALE_L2E 0.12751744f          // log2(e)/sqrt(128)
#define SZ_MAP (BB*CC*NN)              // 2359296 elements
#define NSPLIT 2
#define TILES_PER (18/NSPLIT)

__device__ inline u16 f2bf(float f) {
    unsigned u = __builtin_bit_cast(unsigned, f);
    u = (u + 0x7FFFu + ((u >> 16) & 1u)) >> 16;
    return (u16)u;
}
__device__ inline float bf2f(u16 h) {
    unsigned u = ((unsigned)h) << 16;
    return __builtin_bit_cast(float, u);
}

#define MFMA(a, b, c) __builtin_amdgcn_mfma_f32_16x16x32_bf16(a, b, c, 0, 0, 0)
// DPP rotate-add within each 16-lane row (VALU pipe, no LDS traffic)
#define DPP_ROR_ADD(x, N) { \
    int yi_ = __builtin_amdgcn_update_dpp(0, __builtin_bit_cast(int, x), 0x120 | (N), 0xf, 0xf, true); \
    x += __builtin_bit_cast(float, yi_); }

// ---------------- K1: GroupNorm -> xnT16[b][n][c]  +  weight cast (fused) ----------------
// b = blockIdx.x & 7 so all blocks of batch b land on XCD b (blockid % 8 == b).
__global__ __launch_bounds__(256) void gnprep_kernel(
        const float* __restrict__ x, const float* __restrict__ gw,
        const float* __restrict__ gb, u16* __restrict__ xnT,
        const float* __restrict__ wq, const float* __restrict__ wk,
        const float* __restrict__ wv_, const float* __restrict__ wo,
        u16* __restrict__ w16) {
    int tid = threadIdx.x;
    if (blockIdx.x >= 256) {
        int i = (blockIdx.x - 256) * 256 + tid;   // 0..65535
        int m = i >> 14, r = i & 16383;
        const float* src = (m == 0) ? wq : (m == 1) ? wk : (m == 2) ? wv_ : wo;
        w16[i] = f2bf(src[r]);
        return;
    }
    int b = blockIdx.x & 7, g = blockIdx.x >> 3;
    const float* xb = x + ((size_t)b * CC + g * 4) * NN;
    float v[4][9];
    float s = 0.f, ss = 0.f;
#pragma unroll
    for (int c = 0; c < 4; ++c)
#pragma unroll
        for (int k = 0; k < 9; ++k) {
            float t = xb[c * NN + tid + k * 256];
            v[c][k] = t; s += t; ss += t * t;
        }
#pragma unroll
    for (int o = 32; o > 0; o >>= 1) { s += __shfl_down(s, o); ss += __shfl_down(ss, o); }
    __shared__ float red[8];
    __shared__ float stats[2];
    int wid = tid >> 6;
    if ((tid & 63) == 0) { red[wid * 2] = s; red[wid * 2 + 1] = ss; }
    __syncthreads();
    if (tid == 0) {
        float S = 0.f, SS = 0.f;
        for (int i = 0; i < 4; ++i) { S += red[i * 2]; SS += red[i * 2 + 1]; }
        float mu = S * (1.f / 9216.f);
        float var = SS * (1.f / 9216.f) - mu * mu;
        stats[0] = mu;
        stats[1] = rsqrtf(var + 1e-5f);
    }
    __syncthreads();
    float mu = stats[0], rs = stats[1];
    float sc[4], bi[4];
#pragma unroll
    for (int c = 0; c < 4; ++c) {
        sc[c] = gw[g * 4 + c] * rs;
        bi[c] = gb[g * 4 + c] - mu * sc[c];
    }
#pragma unroll
    for (int k = 0; k < 9; ++k) {
        int n = tid + k * 256;
        ushort4 o;
        o.x = f2bf(v[0][k] * sc[0] + bi[0]);
        o.y = f2bf(v[1][k] * sc[1] + bi[1]);
        o.z = f2bf(v[2][k] * sc[2] + bi[2]);
        o.w = f2bf(v[3][k] * sc[3] + bi[3]);
        *(ushort4*)(xnT + ((size_t)b * NN + n) * CC + g * 4) = o;
    }
}

// ---------------- K2: QKV via MFMA — 3-way z split (z=0: q, z=1: k, z=2: v) ------------
// grid (8, 18, 3) = 432 blocks (1.7/CU). b fastest -> XCD b. Load:MFMA ratio per wave
// preserved (32 weight b128 loads : 64 MFMA). Operand-swapped MFMAs (D rows = 1st arg)
// -> each lane holds 4 consecutive fast-axis elems -> single ushort4 stores.
// q: natural qT[b][n][c], pre-scaled. k: TILED kt2[b][n/32][c/32][slot][c&31],
// slot(n)=((n&4)<<2)+((n&24)>>1)+(n&3). v: TILED vt2[b][n/32][c/16][c&15][n&31].
__global__ __launch_bounds__(256) void qkv_kernel(
        const u16* __restrict__ xnT, const u16* __restrict__ w16,
        const float* __restrict__ bq, const float* __restrict__ bk,
        const float* __restrict__ bv,
        u16* __restrict__ qT, u16* __restrict__ kt2, u16* __restrict__ vt2) {
    int b = blockIdx.x, n0 = blockIdx.y * 128, z = blockIdx.z;
    int tid = threadIdx.x, lane = tid & 63, wvw = tid >> 6;
    int l15 = lane & 15, l4 = lane >> 4;
    const u16* xb = xnT + (size_t)b * NN * CC;

    if (z == 0) {        // ---- Q ----
        const u16* w16q = w16;
        s16x8 xa[2][4];
#pragma unroll
        for (int mf = 0; mf < 2; ++mf)
#pragma unroll
            for (int ks = 0; ks < 4; ++ks)
                xa[mf][ks] = *(const s16x8*)(xb + (size_t)(n0 + wvw * 32 + mf * 16 + l15) * CC + ks * 32 + l4 * 8);
#pragma unroll 2
        for (int nf = 0; nf < 8; ++nf) {
            f32x4 aq[2] = {};
#pragma unroll
            for (int ks = 0; ks < 4; ++ks) {
                s16x8 fq = *(const s16x8*)(w16q + (nf * 16 + l15) * CC + ks * 32 + l4 * 8);
#pragma unroll
                for (int mf = 0; mf < 2; ++mf)
                    aq[mf] = MFMA(fq, xa[mf][ks], aq[mf]);   // rows=co, cols=n
            }
            int cob = nf * 16 + l4 * 4;
            float4 bq4 = *(const float4*)(bq + cob);
#pragma unroll
            for (int mf = 0; mf < 2; ++mf) {
                int n = n0 + wvw * 32 + mf * 16 + l15;
                ushort4 qo;
                qo.x = f2bf((aq[mf][0] + bq4.x) * SCALE_L2E);
                qo.y = f2bf((aq[mf][1] + bq4.y) * SCALE_L2E);
                qo.z = f2bf((aq[mf][2] + bq4.z) * SCALE_L2E);
                qo.w = f2bf((aq[mf][3] + bq4.w) * SCALE_L2E);
                *(ushort4*)(qT + ((size_t)b * NN + n) * CC + cob) = qo;
            }
        }
    } else if (z == 1) { // ---- K ----
        const u16* w16k = w16 + 16384;
        u16* kb = kt2 + (size_t)b * NN * CC;
        s16x8 xa[2][4];
#pragma unroll
        for (int mf = 0; mf < 2; ++mf)
#pragma unroll
            for (int ks = 0; ks < 4; ++ks)
                xa[mf][ks] = *(const s16x8*)(xb + (size_t)(n0 + wvw * 32 + mf * 16 + l15) * CC + ks * 32 + l4 * 8);
        int chunk = blockIdx.y * 4 + wvw;
#pragma unroll 2
        for (int nf = 0; nf < 8; ++nf) {
            f32x4 ak[2] = {};
#pragma unroll
            for (int ks = 0; ks < 4; ++ks) {
                s16x8 fk = *(const s16x8*)(w16k + (nf * 16 + l15) * CC + ks * 32 + l4 * 8);
#pragma unroll
                for (int mf = 0; mf < 2; ++mf)
                    ak[mf] = MFMA(fk, xa[mf][ks], ak[mf]);   // rows=co, cols=n
            }
            int cob = nf * 16 + l4 * 4;
            float4 bk4 = *(const float4*)(bk + cob);
#pragma unroll
            for (int mf = 0; mf < 2; ++mf) {
                int n5 = mf * 16 + l15;
                int slot = ((n5 & 4) << 2) + ((n5 & 24) >> 1) + (n5 & 3);
                ushort4 ko;
                ko.x = f2bf(ak[mf][0] + bk4.x);
                ko.y = f2bf(ak[mf][1] + bk4.y);
                ko.z = f2bf(ak[mf][2] + bk4.z);
                ko.w = f2bf(ak[mf][3] + bk4.w);
                *(ushort4*)(kb + (size_t)chunk * 4096 + (cob >> 5) * 1024 + slot * 32 + (cob & 31)) = ko;
            }
        }
    } else {             // ---- V ----
        const u16* w16v = w16 + 2 * 16384;
        u16* vb = vt2 + (size_t)b * NN * CC;
        s16x8 wa[2][4];
#pragma unroll
        for (int mf = 0; mf < 2; ++mf)
#pragma unroll
            for (int ks = 0; ks < 4; ++ks)
                wa[mf][ks] = *(const s16x8*)(w16v + (wvw * 32 + mf * 16 + l15) * CC + ks * 32 + l4 * 8);
        float bvl[2];
        bvl[0] = bv[wvw * 32 + l15];
        bvl[1] = bv[wvw * 32 + 16 + l15];
#pragma unroll 2
        for (int nf = 0; nf < 8; ++nf) {
            f32x4 av[2] = {};
#pragma unroll
            for (int ks = 0; ks < 4; ++ks) {
                s16x8 xf = *(const s16x8*)(xb + (size_t)(n0 + nf * 16 + l15) * CC + ks * 32 + l4 * 8);
#pragma unroll
                for (int mf = 0; mf < 2; ++mf) av[mf] = MFMA(xf, wa[mf][ks], av[mf]);  // rows=n, cols=c
            }
            int chunk = blockIdx.y * 4 + (nf >> 1);
            int nlo = (nf & 1) * 16 + l4 * 4;
#pragma unroll
            for (int mf = 0; mf < 2; ++mf) {
                ushort4 vo;
                vo.x = f2bf(av[mf][0] + bvl[mf]);
                vo.y = f2bf(av[mf][1] + bvl[mf]);
                vo.z = f2bf(av[mf][2] + bvl[mf]);
                vo.w = f2bf(av[mf][3] + bvl[mf]);
                *(ushort4*)(vb + (size_t)chunk * 4096 + (wvw * 2 + mf) * 512 + l15 * 32 + nlo) = vo;
            }
        }
    }
}

// ---------------- K3: attention — register diet (3 waves/SIMD), laundered Q guard ------
// grid (8, 48, 2): 768 blocks = 1 round at 3 blocks/CU. b fastest -> XCD b.
// Q in LDS (swizzled); K streamed per-ks; V streamed per-cf. The Q-read address is
// laundered through an empty asm (+v) so the compiler cannot re-hoist Q into 48 regs,
// but — unlike a "memory" clobber — K/V global loads remain freely schedulable
// across the iteration.
// S = mfma(K,Q): sf[mf][hf] reg r = S[slot mf*16+4l4+r][h=hf*16+l15]; slot perm makes
// {sf[0][hf], sf[1][hf]} the PV B-frag directly. PV = mfma(V,P) into cacc[cf][hf].
__global__ __launch_bounds__(256, 3) void attn_kernel(
        const u16* __restrict__ qT, const u16* __restrict__ kt2,
        const u16* __restrict__ vt2, u16* __restrict__ part) {
    int b = blockIdx.x, w = blockIdx.y, sp = blockIdx.z;
    int tid = threadIdx.x, lane = tid & 63, wvw = tid >> 6;
    int l15 = lane & 15, l4 = lane >> 4;
    __shared__ float red[4 * 48 * 36];   // 27648 B reduce buffer
    __shared__ u16 qlds[48 * 128];       // 12288 B swizzled Q

    const u16* qb = qT + (size_t)b * NN * CC;
    const u16* kb = kt2 + (size_t)b * NN * CC;
    const u16* vb = vt2 + (size_t)b * NN * CC;

    // stage Q into LDS once: wave wvw writes (hf,ks) pairs with (hf*4+ks)%4 == wvw
#pragma unroll
    for (int pp = 0; pp < 3; ++pp) {
        int pid = pp * 4 + wvw;          // 0..11
        int hf = pid >> 2, ks = pid & 3;
        s16x8 q = *(const s16x8*)(qb + (size_t)((hf * 16 + l15) * WW + w) * CC + ks * 32 + l4 * 8);
        int m = (ks * 4 + l4) ^ (l15 & 7);
        *(s16x8*)(qlds + (hf * 16 + l15) * 128 + m * 8) = q;
    }
    __syncthreads();

    f32x4 cacc[8][3] = {};   // reg r: c = cf*16+4*l4+r ; h = hf*16+l15

    const int tbase = sp * TILES_PER;
    int qoff = 0;                        // stays 0; opaque to the compiler
#pragma unroll 1
    for (int t = tbase; t < tbase + TILES_PER; ++t) {
        asm volatile("" : "+v"(qoff));   // blocks Q-read hoisting, nothing else
        const u16* cb = kb + (size_t)(t * 4 + wvw) * 4096;
        const u16* cv = vb + (size_t)(t * 4 + wvw) * 4096;
        // S = K·Q, K streamed per-ks (contiguous 1KB wave loads), Q from LDS
        f32x4 sf[2][3] = {};
        __builtin_amdgcn_s_setprio(1);
#pragma unroll
        for (int ks = 0; ks < 4; ++ks) {
            s16x8 kf0 = *(const s16x8*)(cb + ks * 1024 + l15 * 32 + l4 * 8);
            s16x8 kf1 = *(const s16x8*)(cb + ks * 1024 + (16 + l15) * 32 + l4 * 8);
#pragma unroll
            for (int hf = 0; hf < 3; ++hf) {
                s16x8 q = *(const s16x8*)(qlds + qoff + (hf * 16 + l15) * 128
                                          + (((ks * 4 + l4) ^ (l15 & 7)) * 8));
                sf[0][hf] = MFMA(kf0, q, sf[0][hf]);
                sf[1][hf] = MFMA(kf1, q, sf[1][hf]);
            }
        }
        __builtin_amdgcn_s_setprio(0);
        // softmax over h: exp2 (log2e folded into q), per-slot den, DPP rotate-reduce
        float pe[2][3][4];
#pragma unroll
        for (int mf = 0; mf < 2; ++mf)
#pragma unroll
            for (int hf = 0; hf < 3; ++hf)
#pragma unroll
                for (int r = 0; r < 4; ++r) pe[mf][hf][r] = __builtin_amdgcn_exp2f(sf[mf][hf][r]);
        float den[2][4];
#pragma unroll
        for (int mf = 0; mf < 2; ++mf)
#pragma unroll
            for (int r = 0; r < 4; ++r)
                den[mf][r] = pe[mf][0][r] + pe[mf][1][r] + pe[mf][2][r];
#pragma unroll
        for (int mf = 0; mf < 2; ++mf)
#pragma unroll
            for (int r = 0; r < 4; ++r) {
                DPP_ROR_ADD(den[mf][r], 1);
                DPP_ROR_ADD(den[mf][r], 2);
                DPP_ROR_ADD(den[mf][r], 4);
                DPP_ROR_ADD(den[mf][r], 8);
            }
        float rd[2][4];
#pragma unroll
        for (int mf = 0; mf < 2; ++mf)
#pragma unroll
            for (int r = 0; r < 4; ++r) rd[mf][r] = __builtin_amdgcn_rcpf(den[mf][r]);
        // P B-frags directly from sf registers (slot permutation pre-applied to K)
        s16x8 pbf[3];
#pragma unroll
        for (int hf = 0; hf < 3; ++hf) {
            unsigned u0, u1, u2, u3;
            float a0 = pe[0][hf][0] * rd[0][0], a1 = pe[0][hf][1] * rd[0][1];
            float a2 = pe[0][hf][2] * rd[0][2], a3 = pe[0][hf][3] * rd[0][3];
            float a4 = pe[1][hf][0] * rd[1][0], a5 = pe[1][hf][1] * rd[1][1];
            float a6 = pe[1][hf][2] * rd[1][2], a7 = pe[1][hf][3] * rd[1][3];
            asm("v_cvt_pk_bf16_f32 %0, %1, %2" : "=v"(u0) : "v"(a0), "v"(a1));
            asm("v_cvt_pk_bf16_f32 %0, %1, %2" : "=v"(u1) : "v"(a2), "v"(a3));
            asm("v_cvt_pk_bf16_f32 %0, %1, %2" : "=v"(u2) : "v"(a4), "v"(a5));
            asm("v_cvt_pk_bf16_f32 %0, %1, %2" : "=v"(u3) : "v"(a6), "v"(a7));
            i32x4 bb2 = { (int)u0, (int)u1, (int)u2, (int)u3 };
            pbf[hf] = __builtin_bit_cast(s16x8, bb2);
        }
        // PV, V streamed per-cf (contiguous 1KB wave loads)
        __builtin_amdgcn_s_setprio(1);
#pragma unroll
        for (int cf = 0; cf < 8; ++cf) {
            s16x8 vf = *(const s16x8*)(cv + cf * 512 + l15 * 32 + l4 * 8);
#pragma unroll
            for (int hf = 0; hf < 3; ++hf)
                cacc[cf][hf] = MFMA(vf, pbf[hf], cacc[cf][hf]);
        }
        __builtin_amdgcn_s_setprio(0);
    }

    // ---- 4-stage round-robin quadrant reduce (27KB buffer) ----
#pragma unroll
    for (int s = 0; s < 4; ++s) {
        if (s) __syncthreads();
#pragma unroll
        for (int q = 0; q < 4; ++q) {
            if (((q - wvw) & 3) == s) {
#pragma unroll
                for (int i = 0; i < 2; ++i) {
                    int cf = 2 * q + i;
#pragma unroll
                    for (int hf = 0; hf < 3; ++hf) {
                        int addr = q * 1728 + (hf * 16 + l15) * 36 + i * 16 + 4 * l4;
                        f32x4* pp = (f32x4*)&red[addr];
                        if (s == 0) *pp = cacc[cf][hf];
                        else { f32x4 tv = *pp; tv += cacc[cf][hf]; *pp = tv; }
                    }
                }
            }
        }
    }
    __syncthreads();
    // final store: wave v owns quadrant v; lane (l4 = h-sub, l15 = c-pair)
    u16* po = part + (size_t)(b * NSPLIT + sp) * NN * CC;
#pragma unroll
    for (int pass = 0; pass < 12; ++pass) {
        int h = pass * 4 + l4;
        int c = wvw * 32 + l15 * 2;
        float2 v2 = *(float2*)&red[wvw * 1728 + h * 36 + l15 * 2];
        unsigned pk;
        asm("v_cvt_pk_bf16_f32 %0, %1, %2" : "=v"(pk) : "v"(v2.x), "v"(v2.y));
        *(unsigned*)(po + (size_t)(h * WW + w) * CC + c) = pk;
    }
}

// ---------------- K4: partial-reduce (2) + out proj + bias + residual ----------------
// grid (8, 18, 2): b fastest -> XCD b; z = co-half (mf 0-3 / 4-7) -> 288 blocks with
// af-loads and MFMAs halved together. Operand-swapped MFMA (D rows = n) -> each lane
// holds 4 consecutive n at fixed co -> float4 residual loads + float4 stores.
__global__ __launch_bounds__(256) void out_kernel(
        const u16* __restrict__ part, const u16* __restrict__ w16o,
        const float* __restrict__ bo, const float* __restrict__ x,
        float* __restrict__ out) {
    int b = blockIdx.x, n0 = blockIdx.y * 128, zh = blockIdx.z;
    int tid = threadIdx.x, lane = tid & 63, wvw = tid >> 6;
    int l15 = lane & 15, l4 = lane >> 4;
    const u16* pb = part + (size_t)b * NSPLIT * NN * CC;
    s16x8 bfr[2][4];
#pragma unroll
    for (int nf = 0; nf < 2; ++nf)
#pragma unroll
        for (int ks = 0; ks < 4; ++ks) {
            size_t off = (size_t)(n0 + wvw * 32 + nf * 16 + l15) * CC + ks * 32 + l4 * 8;
            s16x8 v0 = *(const s16x8*)(pb + off);
            s16x8 v1 = *(const s16x8*)(pb + (size_t)NN * CC + off);
            s16x8 o;
#pragma unroll
            for (int j = 0; j < 8; ++j)
                o[j] = (short)f2bf(bf2f((u16)v0[j]) + bf2f((u16)v1[j]));
            bfr[nf][ks] = o;
        }
#pragma unroll
    for (int mi = 0; mi < 4; ++mi) {
        int mf = zh * 4 + mi;
        s16x8 af[4];
#pragma unroll
        for (int ks = 0; ks < 4; ++ks)
            af[ks] = *(const s16x8*)(w16o + (mf * 16 + l15) * CC + ks * 32 + l4 * 8);
        f32x4 acc[2] = {};
#pragma unroll
        for (int ks = 0; ks < 4; ++ks)
#pragma unroll
            for (int nf = 0; nf < 2; ++nf)
                acc[nf] = MFMA(bfr[nf][ks], af[ks], acc[nf]);   // rows=n, cols=co
        int co = mf * 16 + l15;
        float bol = bo[co];
#pragma unroll
        for (int nf = 0; nf < 2; ++nf) {
            int n = n0 + wvw * 32 + nf * 16 + l4 * 4;
            size_t idx = ((size_t)b * CC + co) * NN + n;
            float4 xr = *(const float4*)(x + idx);
            float4 o4;
            o4.x = acc[nf][0] + bol + xr.x;
            o4.y = acc[nf][1] + bol + xr.y;
            o4.z = acc[nf][2] + bol + xr.z;
            o4.w = acc[nf][3] + bol + xr.w;
            *(float4*)(out + idx) = o4;
        }
    }
}

extern "C" void kernel_launch(void* const* d_in, const int* in_sizes, int n_in,
                              void* d_out, int out_size, void* d_ws, size_t ws_size,
                              hipStream_t stream) {
    const float* x  = (const float*)d_in[0];
    const float* gw = (const float*)d_in[1];
    const float* gb = (const float*)d_in[2];
    const float* wq = (const float*)d_in[3];
    const float* bq = (const float*)d_in[4];
    const float* wk = (const float*)d_in[5];
    const float* bk = (const float*)d_in[6];
    const float* wv_ = (const float*)d_in[7];
    const float* bv = (const float*)d_in[8];
    const float* wo = (const float*)d_in[9];
    const float* bo = (const float*)d_in[10];

    u16* ws   = (u16*)d_ws;
    u16* xnT  = ws;
    u16* qT   = ws + (size_t)SZ_MAP;
    u16* kt2  = ws + (size_t)2 * SZ_MAP;
    u16* vt2  = ws + (size_t)3 * SZ_MAP;
    u16* part = ws + (size_t)4 * SZ_MAP;             // NSPLIT * SZ_MAP bf16
    u16* w16  = ws + (size_t)(4 + NSPLIT) * SZ_MAP;  // 4*16384 bf16
    float* out = (float*)d_out;

    gnprep_kernel<<<512, 256, 0, stream>>>(x, gw, gb, xnT, wq, wk, wv_, wo, w16);
    qkv_kernel<<<dim3(8, 18, 3), 256, 0, stream>>>(xnT, w16, bq, bk, bv, qT, kt2, vt2);
    attn_kernel<<<dim3(8, WW, NSPLIT), 256, 0, stream>>>(qT, kt2, vt2, part);
    out_kernel<<<dim3(8, 18, 2), 256, 0, stream>>>(part, w16 + 3 * 16384, bo, x, out);
}